// Round 1
// baseline (161.170 us; speedup 1.0000x reference)
//
#include <hip/hip_runtime.h>

// PolylineEncoder: h = relu(X@W1+b1); feat = h@W2+b2; masked max over N=64 points.
// B=32 P=512 N=64 C=9 H=128.
// R8: 1 polyline per 2-wave block (grid 16384x128) -> 8 independent blocks/CU
// (was 4x 4-wave blocks), barriers 5->4 (separate Xs region kills the Xs<->Hb
// alias barrier), X staged via global_load_lds width=16 (no ds_write issues),
// f32->bf16 packing via v_cvt_pk_bf16_f32 (1 VALU per pair, was 3), setprio(1)
// around MFMA clusters.  Keeps XOR-swizzled Hb, folded bias, frag-swizzled
// weights, direct mask, P-in-LDS final reduce.

using bf16x8 = __attribute__((ext_vector_type(8))) short;
using f32x4  = __attribute__((ext_vector_type(4))) float;

#define MFMA32(A,B,C) __builtin_amdgcn_mfma_f32_16x16x32_bf16((A),(B),(C),0,0,0)

__device__ __forceinline__ f32x4 vmax4(f32x4 a, f32x4 b) {
  return __builtin_elementwise_max(a, b);
}

__device__ __forceinline__ unsigned short f2bf(float f) {
  union { float f; unsigned int u; } v; v.f = f;
  unsigned int r = v.u + 0x7fffu + ((v.u >> 16) & 1u);  // RNE
  return (unsigned short)(r >> 16);
}

// hardware packed f32->bf16 (RNE), low=a high=b: 1 VALU per 2 elems
__device__ __forceinline__ unsigned int pk2(float a, float b) {
  unsigned int r;
  asm("v_cvt_pk_bf16_f32 %0, %1, %2" : "=v"(r) : "v"(a), "v"(b));
  return r;
}

// ---------------- prep1: mask sniff + frag-swizzled weights ----------------
// ws: w1sw @0 (8KB) | w2sw @8192 (32KB) | flag @40960
__global__ void prep1(const float* __restrict__ W1, const float* __restrict__ W2,
                      const void* __restrict__ mask,
                      unsigned short* __restrict__ w1sw, unsigned short* __restrict__ w2sw,
                      int* __restrict__ flag) {
  int b = blockIdx.x, t = threadIdx.x;
  if (b == 0) {                      // mask storage sniff over 4096 bytes
    __shared__ int cnt;
    if (t == 0) cnt = 0;
    __syncthreads();
    const unsigned char* mb = (const unsigned char*)mask;
    int local = 0;
    for (int i = t * 16; i < t * 16 + 16; i++) local += (mb[i] != 0) ? 1 : 0;
    atomicAdd(&cnt, local);
    __syncthreads();
    if (t == 0) *flag = (cnt > 2800) ? 1 : 0;   // 1 = byte-wise mask, else int32-wise
  } else if (b <= 2) {
    // w1 A-frags (16x16x32): entry e = (wr*4+th)*64 + lane; h=(e>>6)*16+(lane&15)
    int e = (b - 1) * 256 + t;       // 512 entries x 8 halves = 8KB
    int lane = e & 63, grp = e >> 6;
    int li = lane & 15, q = lane >> 4;
    int h = grp * 16 + li;
    int c0 = q * 8;
    #pragma unroll
    for (int j = 0; j < 8; j++) {
      int c = c0 + j;
      w1sw[e * 8 + j] = f2bf((c < 9) ? W1[c * 128 + h] : 0.f);
    }
  } else {
    // w2 A-frags (16x16x32): entry e = (wr*16+ks*4+td)*64 + lane; 8 halves each
    int e = (b - 3) * 256 + t;       // 2048 entries x 8 halves = 32KB
    if (e < 2048) {
      int lane = e & 63, grp = e >> 6;
      int wr = grp >> 4, sub = grp & 15;
      int ks = sub >> 2, td = sub & 3;
      int li = lane & 15, q = lane >> 4;
      int d = wr * 64 + td * 16 + li;
      int h0 = ks * 32 + q * 8;
      #pragma unroll
      for (int j = 0; j < 8; j++)
        w2sw[e * 8 + j] = f2bf(W2[(h0 + j) * 128 + d]);
    }
  }
}

// ---------------- main ----------------
// LDS: Hb [64 m][128 h] bf16 XOR-swizzled = 16384 B  (aliased by P f32 after b2)
//      Xs raw f32 X polyline (576 f32 = 2304 B) at +16384, own region (no alias
//      barrier needed).  Total 18688 B -> 8 blocks/CU; launch_bounds(128,4)
//      gives the 128-reg/wave budget that fits the w2-frag hoist (R4/R7 proven).
__global__ __launch_bounds__(128, 4) void poly_main_k(
    const float* __restrict__ X, const void* __restrict__ mask,
    const float* __restrict__ b1g, const float* __restrict__ b2g,
    const unsigned short* __restrict__ w1sw, const unsigned short* __restrict__ w2sw,
    const int* __restrict__ flagp, float* __restrict__ out)
{
  __shared__ __align__(16) unsigned char smem[18688];
  unsigned short* Hb = (unsigned short*)smem;          // [0,16384)
  float*          P  = (float*)smem;                   // aliases Hb after b2
  float*          Xs = (float*)(smem + 16384);         // [16384,18688)

  const int tid  = threadIdx.x;
  const int lane = tid & 63;
  const int wr   = tid >> 6;             // wave = h/d half
  const int li   = lane & 15, q = lane >> 4;

  // ---- stage X: 144 x 16B via global_load_lds (no ds_write issues) ----
  {
    const char* xg = (const char*)X + (long long)blockIdx.x * 2304;
    unsigned ldsoff = (unsigned)(tid & 64) * 16;       // wave0: 0, wave1: 1024
    __builtin_amdgcn_global_load_lds(
        (const __attribute__((address_space(1))) unsigned int*)(xg + tid * 16),
        (__attribute__((address_space(3))) unsigned int*)((char*)Xs + ldsoff),
        16, 0, 0);
    if (tid < 16)
      __builtin_amdgcn_global_load_lds(
          (const __attribute__((address_space(1))) unsigned int*)(xg + 2048 + tid * 16),
          (__attribute__((address_space(3))) unsigned int*)((char*)Xs + 2048),
          16, 0, 0);
  }

  // ---- mask: direct loads; all 4 per lane sit in one 64B line (byte case) ----
  float mf[4];
  {
    int flag = *flagp;
    long long mb = (long long)blockIdx.x * 64 + li;
    if (flag) {
      const unsigned char* mp = (const unsigned char*)mask;
      #pragma unroll
      for (int tm = 0; tm < 4; tm++) mf[tm] = mp[mb + tm * 16] ? 0.f : -4e9f;
    } else {
      const int* mp = (const int*)mask;
      #pragma unroll
      for (int tm = 0; tm < 4; tm++) mf[tm] = mp[mb + tm * 16] ? 0.f : -4e9f;
    }
  }

  __syncthreads();  // b0: Xs ready (compiler drains vmcnt before s_barrier)

  // ---- layer-1 B-frags from Xs: B[m][k], k=q*8+j, only c<9 nonzero ----
  bf16x8 bx[4];
  #pragma unroll
  for (int tm = 0; tm < 4; tm++) {
    const float* xr = Xs + (tm * 16 + li) * 9;
    union { bf16x8 v; unsigned int u[4]; } uu;
    uu.u[0] = uu.u[1] = uu.u[2] = uu.u[3] = 0u;
    if (q == 0) {
      uu.u[0] = pk2(xr[0], xr[1]); uu.u[1] = pk2(xr[2], xr[3]);
      uu.u[2] = pk2(xr[4], xr[5]); uu.u[3] = pk2(xr[6], xr[7]);
    } else if (q == 1) {
      uu.u[0] = pk2(xr[8], 0.f);
    }
    bx[tm] = uu.v;
  }

  // ---- layer 1, th-outer: bias folded into MFMA C ----
  #pragma unroll
  for (int th = 0; th < 4; th++) {
    bf16x8 a1 = *(const bf16x8*)(w1sw + ((wr * 4 + th) * 64 + lane) * 8);
    f32x4 bv = *(const f32x4*)(b1g + wr * 64 + th * 16 + q * 4);
    f32x4 acc[4];
    #pragma unroll
    for (int tm = 0; tm < 4; tm++) acc[tm] = bv;
    __builtin_amdgcn_s_setprio(1);
    #pragma unroll
    for (int tm = 0; tm < 4; tm++) acc[tm] = MFMA32(a1, bx[tm], acc[tm]);
    __builtin_amdgcn_s_setprio(0);
    // epilogue: relu (packed max), cvt_pk, swizzled H^T write
    // write chunk (16B units): (wr*8 + th*2 + (q>>1)) ^ li, inner (q&1)*8B
    #pragma unroll
    for (int tm = 0; tm < 4; tm++) {
      int m = tm * 16 + li;
      f32x4 v = vmax4(acc[tm], f32x4{0.f, 0.f, 0.f, 0.f});
      uint2 hv;
      hv.x = pk2(v[0], v[1]);
      hv.y = pk2(v[2], v[3]);
      int chunk = (wr * 8 + th * 2 + (q >> 1)) ^ li;
      *(uint2*)(Hb + m * 128 + chunk * 8 + (q & 1) * 4) = hv;
    }
  }
  __syncthreads();  // b1: Hb ready

  // ---- layer 2, tm-outer with incremental pool ----
  f32x4 pooled[4];
  #pragma unroll
  for (int tm = 0; tm < 4; tm++) {
    int m = tm * 16 + li;
    f32x4 acc[4];
    #pragma unroll
    for (int td = 0; td < 4; td++) acc[td] = f32x4{0.f, 0.f, 0.f, 0.f};
    #pragma unroll
    for (int ks = 0; ks < 4; ks++) {
      int chunk = (ks * 4 + q) ^ li;             // read swizzle, 16B aligned
      bf16x8 bb = *(const bf16x8*)(Hb + m * 128 + chunk * 8);
      __builtin_amdgcn_s_setprio(1);
      #pragma unroll
      for (int td = 0; td < 4; td++) {
        bf16x8 a2 = *(const bf16x8*)(w2sw + (((wr * 16 + ks * 4 + td) * 64) + lane) * 8);
        acc[td] = MFMA32(a2, bb, acc[td]);
      }
      __builtin_amdgcn_s_setprio(0);
    }
    if (tm == 0) {
      #pragma unroll
      for (int td = 0; td < 4; td++) pooled[td] = acc[td] + mf[0];
    } else {
      #pragma unroll
      for (int td = 0; td < 4; td++) pooled[td] = vmax4(pooled[td], acc[td] + mf[tm]);
    }
  }
  // bias after max (uniform over m)
  #pragma unroll
  for (int td = 0; td < 4; td++)
    pooled[td] += *(const f32x4*)(b2g + wr * 64 + td * 16 + q * 4);

  __syncthreads();  // b2: all Hb reads done -> reuse arena as P
  // P[li][d] f32, row stride 132 (pad breaks 2^k bank stride)
  #pragma unroll
  for (int td = 0; td < 4; td++)
    *(f32x4*)(P + li * 132 + wr * 64 + td * 16 + q * 4) = pooled[td];
  __syncthreads();  // b3: P ready

  // ---- final: reduce 16 li-partials per d, coalesced full-line store ----
  {
    const float* Pp = P + tid;          // d = tid (0..127)
    float v = Pp[0];
    #pragma unroll
    for (int j = 1; j < 16; j++) v = fmaxf(v, Pp[j * 132]);
    if (v < -1e8f) v = 0.f;
    out[(long long)blockIdx.x * 128 + tid] = v;
  }
}

extern "C" void kernel_launch(void* const* d_in, const int* in_sizes, int n_in,
                              void* d_out, int out_size, void* d_ws, size_t ws_size,
                              hipStream_t stream) {
  const float* X    = (const float*)d_in[0];
  const void*  mask = d_in[1];
  const float* W1   = (const float*)d_in[2];
  const float* b1   = (const float*)d_in[3];
  const float* W2   = (const float*)d_in[4];
  const float* b2   = (const float*)d_in[5];
  float* out = (float*)d_out;

  unsigned short* w1sw = (unsigned short*)d_ws;
  unsigned short* w2sw = (unsigned short*)((char*)d_ws + 8192);
  int* flag            = (int*)((char*)d_ws + 40960);

  prep1<<<11, 256, 0, stream>>>(W1, W2, mask, w1sw, w2sw, flag);
  poly_main_k<<<16384, 128, 0, stream>>>(X, mask, b1, b2, w1sw, w2sw, flag, out);
}

// Round 2
// 145.479 us; speedup vs baseline: 1.1079x; 1.1079x over previous
//
#include <hip/hip_runtime.h>

// PolylineEncoder: h = relu(X@W1+b1); feat = h@W2+b2; masked max over N=64 points.
// B=32 P=512 N=64 C=9 H=128.  Block = 2 polylines (256 thr), grid 8192.
// R9 = R7 base (spill-free codegen, launch_bounds(256,4)) with barrier surgery:
//   - Xs in its own LDS region (37.4KB total, still 4 blocks/CU) -> kills the
//     Xs<->Hb alias barrier.
//   - final pool via 16-lane __shfl_xor reduce -> kills both P-phase barriers
//     and the P LDS round-trip.
//   - X staged via global_load_lds width=16 (no ds_write issues; R8-proven).
//   - v_cvt_pk_bf16_f32 packing (1 VALU per pair; R8-proven).
// Barriers 5 -> 2.  R8 lesson: keep 256-thread blocks (2-wave blocks respilled,
// WRITE_SIZE 12->41MB); no setprio (unattributed).

using bf16x8 = __attribute__((ext_vector_type(8))) short;
using f32x4  = __attribute__((ext_vector_type(4))) float;

#define MFMA32(A,B,C) __builtin_amdgcn_mfma_f32_16x16x32_bf16((A),(B),(C),0,0,0)

__device__ __forceinline__ f32x4 vmax4(f32x4 a, f32x4 b) {
  return __builtin_elementwise_max(a, b);
}

__device__ __forceinline__ unsigned short f2bf(float f) {
  union { float f; unsigned int u; } v; v.f = f;
  unsigned int r = v.u + 0x7fffu + ((v.u >> 16) & 1u);  // RNE
  return (unsigned short)(r >> 16);
}

// hardware packed f32->bf16 (RNE), low=a high=b: 1 VALU per 2 elems
__device__ __forceinline__ unsigned int pk2(float a, float b) {
  unsigned int r;
  asm("v_cvt_pk_bf16_f32 %0, %1, %2" : "=v"(r) : "v"(a), "v"(b));
  return r;
}

__device__ __forceinline__ f32x4 shfl_xor4(f32x4 v, int m) {
  f32x4 r;
  r[0] = __shfl_xor(v[0], m);
  r[1] = __shfl_xor(v[1], m);
  r[2] = __shfl_xor(v[2], m);
  r[3] = __shfl_xor(v[3], m);
  return r;
}

// ---------------- prep1: mask sniff + frag-swizzled weights ----------------
// ws: w1sw @0 (8KB) | w2sw @8192 (32KB) | flag @40960
__global__ void prep1(const float* __restrict__ W1, const float* __restrict__ W2,
                      const void* __restrict__ mask,
                      unsigned short* __restrict__ w1sw, unsigned short* __restrict__ w2sw,
                      int* __restrict__ flag) {
  int b = blockIdx.x, t = threadIdx.x;
  if (b == 0) {                      // mask storage sniff over 4096 bytes
    __shared__ int cnt;
    if (t == 0) cnt = 0;
    __syncthreads();
    const unsigned char* mb = (const unsigned char*)mask;
    int local = 0;
    for (int i = t * 16; i < t * 16 + 16; i++) local += (mb[i] != 0) ? 1 : 0;
    atomicAdd(&cnt, local);
    __syncthreads();
    if (t == 0) *flag = (cnt > 2800) ? 1 : 0;   // 1 = byte-wise mask, else int32-wise
  } else if (b <= 2) {
    // w1 A-frags (16x16x32): entry e = (wr*4+th)*64 + lane; h=(e>>6)*16+(lane&15)
    int e = (b - 1) * 256 + t;       // 512 entries x 8 halves = 8KB
    int lane = e & 63, grp = e >> 6;
    int li = lane & 15, q = lane >> 4;
    int h = grp * 16 + li;
    int c0 = q * 8;
    #pragma unroll
    for (int j = 0; j < 8; j++) {
      int c = c0 + j;
      w1sw[e * 8 + j] = f2bf((c < 9) ? W1[c * 128 + h] : 0.f);
    }
  } else {
    // w2 A-frags (16x16x32): entry e = (wr*16+ks*4+td)*64 + lane; 8 halves each
    int e = (b - 3) * 256 + t;       // 2048 entries x 8 halves = 32KB
    if (e < 2048) {
      int lane = e & 63, grp = e >> 6;
      int wr = grp >> 4, sub = grp & 15;
      int ks = sub >> 2, td = sub & 3;
      int li = lane & 15, q = lane >> 4;
      int d = wr * 64 + td * 16 + li;
      int h0 = ks * 32 + q * 8;
      #pragma unroll
      for (int j = 0; j < 8; j++)
        w2sw[e * 8 + j] = f2bf(W2[(h0 + j) * 128 + d]);
    }
  }
}

// ---------------- main ----------------
// LDS: Hb [128 m][128 h] bf16 XOR-swizzled @0      (32768 B)
//      Xs raw f32 X block (1152 f32)      @32768   ( 4608 B)
// Total 37376 B -> 4 blocks/CU (150KB/160KB).  Only 2 barriers:
//   b0: Xs staged;  b1: Hb ready.
__global__ __launch_bounds__(256, 4) void poly_main_k(
    const float* __restrict__ X, const void* __restrict__ mask,
    const float* __restrict__ b1g, const float* __restrict__ b2g,
    const unsigned short* __restrict__ w1sw, const unsigned short* __restrict__ w2sw,
    const int* __restrict__ flagp, float* __restrict__ out)
{
  __shared__ __align__(16) unsigned char smem[37376];
  unsigned short* Hb = (unsigned short*)smem;          // [0, 32768)
  float*          Xs = (float*)(smem + 32768);         // [32768, 37376)

  const int tid  = threadIdx.x;
  const int lane = tid & 63;
  const int w    = tid >> 6;
  const int wr   = w >> 1, wc = w & 1;   // wr = h/d half, wc = polyline in block
  const int li   = lane & 15, q = lane >> 4;

  // ---- stage X: 288 x 16B via global_load_lds (wave-uniform base + lane*16) ----
  {
    const char* xg = (const char*)X + (long long)blockIdx.x * 4608;
    __builtin_amdgcn_global_load_lds(
        (const __attribute__((address_space(1))) unsigned int*)(xg + tid * 16),
        (__attribute__((address_space(3))) unsigned int*)((char*)Xs + w * 1024),
        16, 0, 0);
    if (tid < 32)
      __builtin_amdgcn_global_load_lds(
          (const __attribute__((address_space(1))) unsigned int*)(xg + 4096 + tid * 16),
          (__attribute__((address_space(3))) unsigned int*)((char*)Xs + 4096),
          16, 0, 0);
  }

  // ---- mask: direct loads; all 4 per lane sit in one 64B line (byte case) ----
  float mf[4];
  {
    int flag = *flagp;
    long long mb = (long long)blockIdx.x * 128 + wc * 64 + li;
    if (flag) {
      const unsigned char* mp = (const unsigned char*)mask;
      #pragma unroll
      for (int tm = 0; tm < 4; tm++) mf[tm] = mp[mb + tm * 16] ? 0.f : -4e9f;
    } else {
      const int* mp = (const int*)mask;
      #pragma unroll
      for (int tm = 0; tm < 4; tm++) mf[tm] = mp[mb + tm * 16] ? 0.f : -4e9f;
    }
  }

  __syncthreads();  // b0: Xs ready (vmcnt drained before s_barrier)

  // ---- layer-1 B-frags from Xs: B[m][k], k=q*8+j, only c<9 nonzero ----
  bf16x8 bx[4];
  #pragma unroll
  for (int tm = 0; tm < 4; tm++) {
    int m = wc * 64 + tm * 16 + li;
    const float* xr = Xs + m * 9;
    union { bf16x8 v; unsigned int u[4]; } uu;
    uu.u[0] = uu.u[1] = uu.u[2] = uu.u[3] = 0u;
    if (q == 0) {
      uu.u[0] = pk2(xr[0], xr[1]); uu.u[1] = pk2(xr[2], xr[3]);
      uu.u[2] = pk2(xr[4], xr[5]); uu.u[3] = pk2(xr[6], xr[7]);
    } else if (q == 1) {
      uu.u[0] = pk2(xr[8], 0.f);
    }
    bx[tm] = uu.v;
  }

  // ---- layer 1, th-outer: bias folded into MFMA C ----
  #pragma unroll
  for (int th = 0; th < 4; th++) {
    bf16x8 a1 = *(const bf16x8*)(w1sw + ((wr * 4 + th) * 64 + lane) * 8);
    f32x4 bv = *(const f32x4*)(b1g + wr * 64 + th * 16 + q * 4);
    f32x4 acc[4];
    #pragma unroll
    for (int tm = 0; tm < 4; tm++) acc[tm] = bv;
    #pragma unroll
    for (int tm = 0; tm < 4; tm++) acc[tm] = MFMA32(a1, bx[tm], acc[tm]);
    // epilogue: relu (packed max), cvt_pk, swizzled H^T write
    // write chunk (16B units): (wr*8 + th*2 + (q>>1)) ^ li, inner (q&1)*8B
    #pragma unroll
    for (int tm = 0; tm < 4; tm++) {
      int m = wc * 64 + tm * 16 + li;
      f32x4 v = vmax4(acc[tm], f32x4{0.f, 0.f, 0.f, 0.f});
      uint2 hv;
      hv.x = pk2(v[0], v[1]);
      hv.y = pk2(v[2], v[3]);
      int chunk = (wr * 8 + th * 2 + (q >> 1)) ^ li;
      *(uint2*)(Hb + m * 128 + chunk * 8 + (q & 1) * 4) = hv;
    }
  }
  __syncthreads();  // b1: Hb ready

  // ---- layer 2, tm-outer with incremental pool ----
  f32x4 pooled[4];
  #pragma unroll
  for (int tm = 0; tm < 4; tm++) {
    int m = wc * 64 + tm * 16 + li;
    f32x4 acc[4];
    #pragma unroll
    for (int td = 0; td < 4; td++) acc[td] = f32x4{0.f, 0.f, 0.f, 0.f};
    #pragma unroll
    for (int ks = 0; ks < 4; ks++) {
      int chunk = (ks * 4 + q) ^ li;             // read swizzle, 16B aligned
      bf16x8 bb = *(const bf16x8*)(Hb + m * 128 + chunk * 8);
      #pragma unroll
      for (int td = 0; td < 4; td++) {
        bf16x8 a2 = *(const bf16x8*)(w2sw + (((wr * 16 + ks * 4 + td) * 64) + lane) * 8);
        acc[td] = MFMA32(a2, bb, acc[td]);
      }
    }
    if (tm == 0) {
      #pragma unroll
      for (int td = 0; td < 4; td++) pooled[td] = acc[td] + mf[0];
    } else {
      #pragma unroll
      for (int td = 0; td < 4; td++) pooled[td] = vmax4(pooled[td], acc[td] + mf[tm]);
    }
  }

  // ---- final pool over li: 16-lane shuffle reduce (xor 1,2,4,8), no LDS ----
  #pragma unroll
  for (int td = 0; td < 4; td++) {
    #pragma unroll
    for (int sm = 1; sm < 16; sm <<= 1)
      pooled[td] = vmax4(pooled[td], shfl_xor4(pooled[td], sm));
  }

  // li==0 lanes hold the full pool; add bias, zero-fix, coalesced 16B stores
  if (li == 0) {
    float* op = out + (long long)blockIdx.x * 256 + wc * 128 + wr * 64 + q * 4;
    #pragma unroll
    for (int td = 0; td < 4; td++) {
      f32x4 v = pooled[td] + *(const f32x4*)(b2g + wr * 64 + td * 16 + q * 4);
      #pragma unroll
      for (int j = 0; j < 4; j++) if (v[j] < -1e8f) v[j] = 0.f;
      *(f32x4*)(op + td * 16) = v;
    }
  }
}

extern "C" void kernel_launch(void* const* d_in, const int* in_sizes, int n_in,
                              void* d_out, int out_size, void* d_ws, size_t ws_size,
                              hipStream_t stream) {
  const float* X    = (const float*)d_in[0];
  const void*  mask = d_in[1];
  const float* W1   = (const float*)d_in[2];
  const float* b1   = (const float*)d_in[3];
  const float* W2   = (const float*)d_in[4];
  const float* b2   = (const float*)d_in[5];
  float* out = (float*)d_out;

  unsigned short* w1sw = (unsigned short*)d_ws;
  unsigned short* w2sw = (unsigned short*)((char*)d_ws + 8192);
  int* flag            = (int*)((char*)d_ws + 40960);

  prep1<<<11, 256, 0, stream>>>(W1, W2, mask, w1sw, w2sw, flag);
  poly_main_k<<<8192, 256, 0, stream>>>(X, mask, b1, b2, w1sw, w2sw, flag, out);
}